// Round 1
// baseline (46.468 us; speedup 1.0000x reference)
//
#include <hip/hip_runtime.h>

// GradLoss: grad_loss = mean((sobelx(t)-sobelx(o))^2) + mean((sobely(t)-sobely(o))^2)
// Linearity: = mean(sobelx(t-o)^2) + mean(sobely(t-o)^2). Single fused pass.
// B=32, C=1, H=W=512, fp32. lax.conv_general_dilated = cross-correlation (no flip).

#define BATCH 32
#define HH 512
#define WW 512
#define RROWS 8          // rows per block tile
#define TPB 256

__global__ __launch_bounds__(TPB) void sobel_grad_loss_kernel(
    const float* __restrict__ out_img,
    const float* __restrict__ tgt_img,
    float* __restrict__ result)
{
    // d-tile: (R+2) rows x (W+2) cols, zero-padded columns at [0] and [W+1]
    __shared__ float lds[RROWS + 2][WW + 2];
    __shared__ float wsum[TPB / 64];

    const int tid = threadIdx.x;
    const int bid = blockIdx.x;
    const int tilesPerImg = HH / RROWS;            // 64
    const int b  = bid / tilesPerImg;
    const int y0 = (bid % tilesPerImg) * RROWS;
    const size_t imgBase = (size_t)b * HH * WW;

    // zero the padding columns (rows 0..R+1)
    if (tid < RROWS + 2) { lds[tid][0] = 0.f; lds[tid][WW + 1] = 0.f; }

    // stage d = target - output for global rows y0-1 .. y0+R (zeros outside image)
    // (R+2) rows * (W/4) float4 quads = 10*128 = 1280, 5 per thread
    #pragma unroll
    for (int i = tid; i < (RROWS + 2) * (WW / 4); i += TPB) {
        const int r  = i >> 7;        // / (W/4)=128
        const int c4 = i & 127;
        const int g  = y0 - 1 + r;
        const int c  = c4 * 4;
        if ((unsigned)g < (unsigned)HH) {
            const float4 o = *(const float4*)(out_img + imgBase + (size_t)g * WW + c);
            const float4 t = *(const float4*)(tgt_img + imgBase + (size_t)g * WW + c);
            lds[r][c + 1] = t.x - o.x;
            lds[r][c + 2] = t.y - o.y;
            lds[r][c + 3] = t.z - o.z;
            lds[r][c + 4] = t.w - o.w;
        } else {
            lds[r][c + 1] = 0.f;
            lds[r][c + 2] = 0.f;
            lds[r][c + 3] = 0.f;
            lds[r][c + 4] = 0.f;
        }
    }
    __syncthreads();

    // Each thread owns W/TPB = 2 columns; vertical register rolling:
    // per pixel only the new bottom row triple is read from LDS (3 reads/px).
    float acc = 0.f;
    #pragma unroll
    for (int cc = 0; cc < WW / TPB; ++cc) {
        const int xi = cc * TPB + tid + 1;         // LDS col (shifted by pad)
        float a0 = lds[0][xi - 1], b0 = lds[0][xi], c0 = lds[0][xi + 1];
        float a1 = lds[1][xi - 1], b1 = lds[1][xi], c1 = lds[1][xi + 1];
        #pragma unroll
        for (int r = 0; r < RROWS; ++r) {
            const float a2 = lds[r + 2][xi - 1];
            const float b2 = lds[r + 2][xi];
            const float c2 = lds[r + 2][xi + 1];
            // KX = [[-1,0,1],[-2,0,2],[-1,0,1]] (cross-correlation)
            const float gx = (c0 - a0) + 2.f * (c1 - a1) + (c2 - a2);
            // KY = [[1,2,1],[0,0,0],[-1,-2,-1]]
            const float gy = (a0 + 2.f * b0 + c0) - (a2 + 2.f * b2 + c2);
            acc = fmaf(gx, gx, acc);
            acc = fmaf(gy, gy, acc);
            a0 = a1; b0 = b1; c0 = c1;
            a1 = a2; b1 = b2; c1 = c2;
        }
    }

    // wave (64-lane) reduction, then cross-wave via LDS
    #pragma unroll
    for (int off = 32; off > 0; off >>= 1)
        acc += __shfl_down(acc, off, 64);
    const int wid = tid >> 6;
    if ((tid & 63) == 0) wsum[wid] = acc;
    __syncthreads();
    if (tid == 0) {
        const float s = wsum[0] + wsum[1] + wsum[2] + wsum[3];
        atomicAdd(result, s * (1.0f / ((float)BATCH * HH * WW)));
    }
}

extern "C" void kernel_launch(void* const* d_in, const int* in_sizes, int n_in,
                              void* d_out, int out_size, void* d_ws, size_t ws_size,
                              hipStream_t stream) {
    (void)in_sizes; (void)n_in; (void)d_ws; (void)ws_size; (void)out_size;
    const float* out_img = (const float*)d_in[0];   // "output"
    const float* tgt_img = (const float*)d_in[1];   // "target"
    float* res = (float*)d_out;

    // harness does not re-zero d_out between timed replays
    hipMemsetAsync(res, 0, sizeof(float), stream);

    const int grid = BATCH * (HH / RROWS);          // 2048 blocks
    sobel_grad_loss_kernel<<<grid, TPB, 0, stream>>>(out_img, tgt_img, res);
}

// Round 2
// 20.492 us; speedup vs baseline: 2.2676x; 2.2676x over previous
//
#include <hip/hip_runtime.h>

// GradLoss: mean((sobelx(t)-sobelx(o))^2) + mean((sobely(t)-sobely(o))^2)
// Linearity: = mean(sobelx(d)^2) + mean(sobely(d)^2) with d = t - o.
// Two-stage: stage1 per-block partials -> d_ws (no same-address atomic storm),
// stage2 reduces partials -> d_out. B=32, H=W=512, fp32.

#define BATCH 32
#define HH 512
#define WW 512
#define RROWS 16                 // rows per block tile
#define TPB 256
#define LSTRIDE (WW + 8)         // 520 floats: data at cols [4, 516), halos at 3 and 516
#define NPART (BATCH * (HH / RROWS))   // 1024 partials

__global__ __launch_bounds__(TPB) void sobel_partial_kernel(
    const float* __restrict__ out_img,
    const float* __restrict__ tgt_img,
    float* __restrict__ partials)
{
    __shared__ float lds[(RROWS + 2) * LSTRIDE];
    __shared__ float wsum[TPB / 64];

    const int tid = threadIdx.x;
    const int bid = blockIdx.x;
    const int tilesPerImg = HH / RROWS;            // 32
    const int b  = bid / tilesPerImg;
    const int y0 = (bid % tilesPerImg) * RROWS;
    const size_t imgBase = (size_t)b * HH * WW;

    // zero the halo columns (cols 3 and 516) for all staged rows
    if (tid < RROWS + 2) {
        lds[tid * LSTRIDE + 3]      = 0.f;
        lds[tid * LSTRIDE + WW + 4] = 0.f;
    }

    // stage d = target - output for global rows y0-1 .. y0+RROWS (zeros outside)
    // (RROWS+2)*128 quads = 2304, 9 per thread; float4 LDS writes, 16B aligned,
    // consecutive lanes -> consecutive addresses: conflict-free ds_write_b128.
    #pragma unroll
    for (int i = tid; i < (RROWS + 2) * (WW / 4); i += TPB) {
        const int r  = i >> 7;                     // / 128
        const int c4 = i & 127;
        const int g  = y0 - 1 + r;
        const int c  = c4 * 4;
        float4 d4;
        if ((unsigned)g < (unsigned)HH) {
            const float4 o = *(const float4*)(out_img + imgBase + (size_t)g * WW + c);
            const float4 t = *(const float4*)(tgt_img + imgBase + (size_t)g * WW + c);
            d4 = make_float4(t.x - o.x, t.y - o.y, t.z - o.z, t.w - o.w);
        } else {
            d4 = make_float4(0.f, 0.f, 0.f, 0.f);
        }
        *(float4*)(lds + r * LSTRIDE + 4 + c) = d4;
    }
    __syncthreads();

    // Each thread owns WW/TPB = 2 columns; vertical register rolling
    // (3 LDS reads per new row, stride-1 across lanes: conflict-free).
    float acc = 0.f;
    #pragma unroll
    for (int cc = 0; cc < WW / TPB; ++cc) {
        const int xi = 4 + cc * TPB + tid;         // LDS col of this thread's pixel
        const float* p = lds + xi;
        float a0 = p[-1],            b0 = p[0],            c0 = p[1];
        float a1 = p[LSTRIDE - 1],   b1 = p[LSTRIDE],      c1 = p[LSTRIDE + 1];
        #pragma unroll
        for (int r = 0; r < RROWS; ++r) {
            const float* q = p + (r + 2) * LSTRIDE;
            const float a2 = q[-1];
            const float b2 = q[0];
            const float c2 = q[1];
            // KX = [[-1,0,1],[-2,0,2],[-1,0,1]]  (cross-correlation)
            const float gx = (c0 - a0) + 2.f * (c1 - a1) + (c2 - a2);
            // KY = [[1,2,1],[0,0,0],[-1,-2,-1]]
            const float gy = (a0 + 2.f * b0 + c0) - (a2 + 2.f * b2 + c2);
            acc = fmaf(gx, gx, acc);
            acc = fmaf(gy, gy, acc);
            a0 = a1; b0 = b1; c0 = c1;
            a1 = a2; b1 = b2; c1 = c2;
        }
    }

    // wave reduction, then cross-wave via LDS; one plain store per block
    #pragma unroll
    for (int off = 32; off > 0; off >>= 1)
        acc += __shfl_down(acc, off, 64);
    const int wid = tid >> 6;
    if ((tid & 63) == 0) wsum[wid] = acc;
    __syncthreads();
    if (tid == 0)
        partials[bid] = wsum[0] + wsum[1] + wsum[2] + wsum[3];
}

__global__ __launch_bounds__(TPB) void reduce_partials_kernel(
    const float* __restrict__ partials, float* __restrict__ out)
{
    const int tid = threadIdx.x;
    float s = 0.f;
    #pragma unroll
    for (int i = 0; i < NPART / TPB; ++i)
        s += partials[tid + i * TPB];
    #pragma unroll
    for (int off = 32; off > 0; off >>= 1)
        s += __shfl_down(s, off, 64);
    __shared__ float w[TPB / 64];
    if ((tid & 63) == 0) w[tid >> 6] = s;
    __syncthreads();
    if (tid == 0)
        out[0] = (w[0] + w[1] + w[2] + w[3]) * (1.0f / ((float)BATCH * HH * WW));
}

extern "C" void kernel_launch(void* const* d_in, const int* in_sizes, int n_in,
                              void* d_out, int out_size, void* d_ws, size_t ws_size,
                              hipStream_t stream) {
    (void)in_sizes; (void)n_in; (void)ws_size; (void)out_size;
    const float* out_img = (const float*)d_in[0];   // "output"
    const float* tgt_img = (const float*)d_in[1];   // "target"
    float* partials = (float*)d_ws;                 // NPART floats of scratch
    float* res = (float*)d_out;

    sobel_partial_kernel<<<NPART, TPB, 0, stream>>>(out_img, tgt_img, partials);
    reduce_partials_kernel<<<1, TPB, 0, stream>>>(partials, res);
}

// Round 3
// 19.839 us; speedup vs baseline: 2.3422x; 1.0329x over previous
//
#include <hip/hip_runtime.h>

// GradLoss: mean((sobelx(t)-sobelx(o))^2) + mean((sobely(t)-sobely(o))^2)
//         = mean(sobelx(d)^2) + mean(sobely(d)^2), d = t - o   (linearity)
// Stage1: LDS-free, barrier-free. Each wave owns a 512-wide x 16-row strip:
//   2 float4 slots per lane cover the full row; horizontal halo via intra-wave
//   shuffles; vertical via register rolling (ring buffer, fully unrolled).
//   Separable stencil: row pass s=a+2b+c, dd=c-a; col pass gx=dd0+2dd1+dd2,
//   gy=s0-s2. One partial per wave -> d_ws.
// Stage2: one block reduces 1024 partials -> d_out.

#define BATCH 32
#define HH 512
#define WW 512
#define RW 16                       // output rows per wave
#define TPB 256
#define NPART (BATCH * (HH / RW))   // 1024 partials (one per wave)

__global__ __launch_bounds__(TPB) void sobel_partial_kernel(
    const float* __restrict__ out_img,
    const float* __restrict__ tgt_img,
    float* __restrict__ partials)
{
    const int tid  = threadIdx.x;
    const int lane = tid & 63;
    const int w    = blockIdx.x * (TPB / 64) + (tid >> 6);  // global wave id, 0..1023
    const int img  = w >> 5;                                // 32 chunks per image
    const int y0   = (w & 31) * RW;

    const size_t base = (size_t)img * HH * WW;
    const float* ob = out_img + base;
    const float* tb = tgt_img + base;
    const int x1 = lane * 4;         // slot1 cols [x1, x1+3]
    const int x2 = 256 + lane * 4;   // slot2 cols

    float hs[3][8];   // ring-buffered row values, indices compile-time after unroll
    float hd[3][8];
    float acc = 0.f;

    #pragma unroll
    for (int i = 0; i < RW + 2; ++i) {
        const int g   = y0 - 1 + i;          // global row being loaded
        const int cur = i % 3;

        float4 d1, d2;
        if ((unsigned)g < (unsigned)HH) {    // wave-uniform branch
            const float* orow = ob + (size_t)g * WW;
            const float* trow = tb + (size_t)g * WW;
            const float4 o1 = *(const float4*)(orow + x1);
            const float4 t1 = *(const float4*)(trow + x1);
            const float4 o2 = *(const float4*)(orow + x2);
            const float4 t2 = *(const float4*)(trow + x2);
            d1 = make_float4(t1.x - o1.x, t1.y - o1.y, t1.z - o1.z, t1.w - o1.w);
            d2 = make_float4(t2.x - o2.x, t2.y - o2.y, t2.z - o2.z, t2.w - o2.w);
        } else {
            d1 = make_float4(0.f, 0.f, 0.f, 0.f);
            d2 = make_float4(0.f, 0.f, 0.f, 0.f);
        }

        // horizontal halos via intra-wave shuffles
        float dl1 = __shfl_up(d1.w, 1, 64);       // lane-1's col x1-1
        if (lane == 0) dl1 = 0.f;                 // image left edge (zero pad)
        const float s2x = __shfl(d2.x, 0, 64);    // col 256 (slot2, lane 0)
        float dr1 = __shfl_down(d1.x, 1, 64);
        if (lane == 63) dr1 = s2x;                // slot1->slot2 seam
        const float s1w = __shfl(d1.w, 63, 64);   // col 255 (slot1, lane 63)
        float dl2 = __shfl_up(d2.w, 1, 64);
        if (lane == 0) dl2 = s1w;                 // slot2<-slot1 seam
        float dr2 = __shfl_down(d2.x, 1, 64);
        if (lane == 63) dr2 = 0.f;                // image right edge (zero pad)

        // row pass: s = L + 2*m + R (for gy), dd = R - L (for gx)
        hs[cur][0] = fmaf(2.f, d1.x, dl1 + d1.y);  hd[cur][0] = d1.y - dl1;
        hs[cur][1] = fmaf(2.f, d1.y, d1.x + d1.z); hd[cur][1] = d1.z - d1.x;
        hs[cur][2] = fmaf(2.f, d1.z, d1.y + d1.w); hd[cur][2] = d1.w - d1.y;
        hs[cur][3] = fmaf(2.f, d1.w, d1.z + dr1);  hd[cur][3] = dr1 - d1.z;
        hs[cur][4] = fmaf(2.f, d2.x, dl2 + d2.y);  hd[cur][4] = d2.y - dl2;
        hs[cur][5] = fmaf(2.f, d2.y, d2.x + d2.z); hd[cur][5] = d2.z - d2.x;
        hs[cur][6] = fmaf(2.f, d2.z, d2.y + d2.w); hd[cur][6] = d2.w - d2.y;
        hs[cur][7] = fmaf(2.f, d2.w, d2.z + dr2);  hd[cur][7] = dr2 - d2.z;

        // column pass for the middle row of the 3-row window
        if (i >= 2) {
            const int top = (i - 2) % 3;
            const int mid = (i - 1) % 3;
            #pragma unroll
            for (int j = 0; j < 8; ++j) {
                const float gx = fmaf(2.f, hd[mid][j], hd[top][j] + hd[cur][j]);
                const float gy = hs[top][j] - hs[cur][j];
                acc = fmaf(gx, gx, acc);
                acc = fmaf(gy, gy, acc);
            }
        }
    }

    // wave reduction; one plain store per wave, no LDS, no barrier
    #pragma unroll
    for (int off = 32; off > 0; off >>= 1)
        acc += __shfl_down(acc, off, 64);
    if (lane == 0)
        partials[w] = acc;
}

__global__ __launch_bounds__(TPB) void reduce_partials_kernel(
    const float* __restrict__ partials, float* __restrict__ out)
{
    const int tid = threadIdx.x;
    float s = 0.f;
    #pragma unroll
    for (int i = 0; i < NPART / TPB; ++i)
        s += partials[tid + i * TPB];
    #pragma unroll
    for (int off = 32; off > 0; off >>= 1)
        s += __shfl_down(s, off, 64);
    __shared__ float wsum[TPB / 64];
    if ((tid & 63) == 0) wsum[tid >> 6] = s;
    __syncthreads();
    if (tid == 0)
        out[0] = (wsum[0] + wsum[1] + wsum[2] + wsum[3])
               * (1.0f / ((float)BATCH * HH * WW));
}

extern "C" void kernel_launch(void* const* d_in, const int* in_sizes, int n_in,
                              void* d_out, int out_size, void* d_ws, size_t ws_size,
                              hipStream_t stream) {
    (void)in_sizes; (void)n_in; (void)ws_size; (void)out_size;
    const float* out_img = (const float*)d_in[0];   // "output"
    const float* tgt_img = (const float*)d_in[1];   // "target"
    float* partials = (float*)d_ws;
    float* res = (float*)d_out;

    sobel_partial_kernel<<<NPART / (TPB / 64), TPB, 0, stream>>>(out_img, tgt_img, partials);
    reduce_partials_kernel<<<1, TPB, 0, stream>>>(partials, res);
}